// Round 10
// baseline (304.484 us; speedup 1.0000x reference)
//
#include <hip/hip_runtime.h>

// PatchTrainer: paint 100 filled circles (last-wins) over a 3x4096x4096 fp32 image.
// Per pixel: out = colors[max covering dot] else patch. Write-streaming.
// R7: nt stores (best so far: 304.4 -> R9 302.7 us; kernel share ~58 us @3.5TB/s)
// R8: profile datum: latency/issue-bound (1.1TB/s, VALU 40%, FETCH 2MB).
// Fill datum: 6.5 TB/s at 9.9% occupancy, 4.9% VALUBusy => stores need a clear
// issue pipe, not more waves. Our ~90 cyc of loop issue per 16B store is the gap.
// R10: (a) AoS float4 dot params -> 1 ds_read_b128/dot (vs 3 ds_read_b32);
//      (b) wave-uniform ENDPOINT classification, exact in fp32 integer range:
//          both segment endpoints inside -> dot covers whole 256px segment ->
//          resolve & break (descending scan => done after ~1-2 dots);
//          both outside & center not interior -> skip, no per-pixel work;
//          else partial -> exact per-pixel test (bit-identical to reference).

#define IMG  4096
#define ND   100
#define TW   256   // tile width  (64 lanes x float4 = one full row per wave)
#define TH   32    // tile height (4 waves, 8 iterations of 4 rows)
#define NBX  (IMG / TW)          // 16
#define NBY  (IMG / TH)          // 128

typedef float vfloat4 __attribute__((ext_vector_type(4)));

__global__ __launch_bounds__(256) void patch_dots_kernel(
    const float* __restrict__ patch,    // [3][4096][4096]
    const float* __restrict__ centers,  // [100][2] (x, y)
    const float* __restrict__ radii,    // [100]
    const float* __restrict__ colors,   // [100][3]
    float* __restrict__ out)            // [3][4096][4096]
{
    // Compacted per-tile dot params, AoS: {xc, yc, r2, col} per dot.
    __shared__ float4 s_dot[ND];
    __shared__ unsigned long long s_mask[2];
    __shared__ int s_cnt;

    // 1D grid decode: x fastest, then y-tile, plane slowest (phase-separated).
    const int bid = blockIdx.x;
    const int bx  = bid % NBX;
    const int by  = (bid / NBX) % NBY;
    const int z   = bid / (NBX * NBY);   // color plane

    const int tx0 = bx * TW;
    const int ty0 = by * TH;
    const int t   = threadIdx.x;
    const int lane = t & 63;
    const int w    = t >> 6;

    const size_t plane = (size_t)z * IMG * IMG;

    // Cull + stage: params in registers, compaction scatters to LDS (AoS).
    int flag = 0;
    float xc = 0.f, yc = 0.f, r2 = 0.f, col = 0.f;
    if (t < ND) {
        // Bit-exact replication of the reference's fp32 math:
        xc = floorf(centers[2 * t]     * 4096.0f);
        yc = floorf(centers[2 * t + 1] * 4096.0f);
        float r = floorf(radii[t] * (4096.0f / 5.0f));
        r2 = r * r;
        col = colors[3 * t + z];
        // Nearest pixel of this tile to the (integer-valued) center:
        float cx = fminf(fmaxf(xc, (float)tx0), (float)(tx0 + TW - 1));
        float cy = fminf(fmaxf(yc, (float)ty0), (float)(ty0 + TH - 1));
        float dx = xc - cx, dy = yc - cy;
        flag = (dx * dx + dy * dy <= r2) ? 1 : 0;
    }
    // Ordered compaction via ballot (waves 0,1 hold dots 0..63, 64..99).
    if (t < 128) {
        unsigned long long m = __ballot(flag != 0);
        if (lane == 0) s_mask[w] = m;
    }
    __syncthreads();
    {
        const unsigned long long m0 = s_mask[0];
        if (flag) {
            const unsigned long long mw = s_mask[w];
            int pos = __popcll(mw & ((1ull << lane) - 1)) + (w ? __popcll(m0) : 0);
            s_dot[pos] = make_float4(xc, yc, r2, col);
        }
        if (t == 0) s_cnt = __popcll(m0) + __popcll(s_mask[1]);
    }
    __syncthreads();
    const int cnt = s_cnt;

    const int x0   = tx0 + lane * 4;
    const float fx0 = (float)x0;
    const float fx1 = (float)(x0 + 1);
    const float fx2 = (float)(x0 + 2);
    const float fx3 = (float)(x0 + 3);
    const float fxL = (float)tx0;             // wave segment endpoints (uniform)
    const float fxR = (float)(tx0 + TW - 1);

    for (int it = 0; it < TH / 4; ++it) {
        const int   y  = ty0 + it * 4 + w;
        const float fy = (float)y;

        // Descending scan: first hit == last-drawn winner.
        int b0 = -1, b1 = -1, b2 = -1, b3 = -1;
        for (int k = cnt - 1; k >= 0; --k) {
            const float4 d  = s_dot[k];        // one ds_read_b128
            const float dy  = fy - d.y;
            const float t2  = d.z - dy * dy;   // exact int arithmetic in fp32
            const float dl  = fxL - d.x;
            const float dr  = fxR - d.x;
            const bool  eL  = (dl * dl <= t2);
            const bool  eR  = (dr * dr <= t2);
            if (eL && eR) {
                // Dot covers the entire 256px segment (convexity, exact):
                // resolve every remaining pixel with k and stop scanning.
                if (b0 < 0) b0 = k;
                if (b1 < 0) b1 = k;
                if (b2 < 0) b2 = k;
                if (b3 < 0) b3 = k;
                break;
            }
            // No pixel of the segment can hit? (min of (x-xc)^2 over segment is
            // at an endpoint when xc outside, at xc itself when inside)
            if (!eL && !eR && !(t2 >= 0.f && d.x >= fxL && d.x <= fxR)) continue;
            // Partial overlap: exact per-pixel tests (bit-identical to reference).
            const float dx0 = fx0 - d.x;
            const float dx1 = fx1 - d.x;
            const float dx2 = fx2 - d.x;
            const float dx3 = fx3 - d.x;
            if (b0 < 0 && dx0 * dx0 <= t2) b0 = k;
            if (b1 < 0 && dx1 * dx1 <= t2) b1 = k;
            if (b2 < 0 && dx2 * dx2 <= t2) b2 = k;
            if (b3 < 0 && dx3 * dx3 <= t2) b3 = k;
            if (__all((b0 | b1 | b2 | b3) >= 0)) break;
        }

        const size_t base = plane + (size_t)y * IMG + x0;

        // Patch (this plane only) needed where no dot covers (~1.5% of pixels).
        float4 p = make_float4(0.f, 0.f, 0.f, 0.f);
        if ((b0 | b1 | b2 | b3) < 0) {
            const vfloat4 pv = __builtin_nontemporal_load((const vfloat4*)(patch + base));
            p = make_float4(pv.x, pv.y, pv.z, pv.w);
        }

        vfloat4 o;
        o.x = (b0 >= 0) ? s_dot[b0].w : p.x;
        o.y = (b1 >= 0) ? s_dot[b1].w : p.y;
        o.z = (b2 >= 0) ? s_dot[b2].w : p.z;
        o.w = (b3 >= 0) ? s_dot[b3].w : p.w;

        __builtin_nontemporal_store(o, (vfloat4*)(out + base));
    }
}

extern "C" void kernel_launch(void* const* d_in, const int* in_sizes, int n_in,
                              void* d_out, int out_size, void* d_ws, size_t ws_size,
                              hipStream_t stream) {
    const float* patch   = (const float*)d_in[0];
    const float* centers = (const float*)d_in[1];
    const float* radii   = (const float*)d_in[2];
    const float* colors  = (const float*)d_in[3];
    float* out = (float*)d_out;

    dim3 grid(NBX * NBY * 3);  // 6144 blocks, 1D (24/CU)
    dim3 block(256);
    patch_dots_kernel<<<grid, block, 0, stream>>>(patch, centers, radii, colors, out);
}